// Round 6
// baseline (654.941 us; speedup 1.0000x reference)
//
#include <hip/hip_runtime.h>
#include <hip/hip_bf16.h>

// Problem constants
#define NLOC 512
#define NALL 640
#define NNEI 96
#define ASEL 20
#define NDIM 128
#define EDIM 64
#define ADIM 64

typedef short bf16x8 __attribute__((ext_vector_type(8)));
typedef float f32x4 __attribute__((ext_vector_type(4)));
typedef unsigned short ushort8 __attribute__((ext_vector_type(8)));

__device__ __forceinline__ unsigned short f2bf(float f) {
    unsigned int u = __float_as_uint(f);
    unsigned int r = (u + 0x7FFFu + ((u >> 16) & 1u)) >> 16;
    return (unsigned short)r;
}

__device__ __forceinline__ float silu(float x) { return x / (1.0f + __expf(-x)); }

// convert 8 consecutive f32 -> 8 bf16, store 16B to LDS
__device__ __forceinline__ void cvt8_store(unsigned short* dst, const float* src) {
    float4 f0 = *(const float4*)src;
    float4 f1 = *(const float4*)(src + 4);
    ushort8 v;
    v[0] = f2bf(f0.x); v[1] = f2bf(f0.y); v[2] = f2bf(f0.z); v[3] = f2bf(f0.w);
    v[4] = f2bf(f1.x); v[5] = f2bf(f1.y); v[6] = f2bf(f1.z); v[7] = f2bf(f1.w);
    *(ushort8*)dst = v;
}

// ---------------- prep: build N-major (transposed) weight matrices in ws ----------------
// bt_edge: [384][320]  n<128: w_edge1 | n<192: w_lin2 | n<256: pad | n<384: w_proj(k>=256)
// bt_ang : [128][320]  n<64: w_ang | n<128: w_ga1
__global__ void prep_bt(const float* __restrict__ w_edge1, const float* __restrict__ w_lin2,
                        const float* __restrict__ w_proj, const float* __restrict__ w_ang,
                        const float* __restrict__ w_ga1, float* __restrict__ bt_edge,
                        float* __restrict__ bt_ang) {
    int idx = blockIdx.x * 256 + threadIdx.x;
    const int total_e = 384 * 320;
    if (idx < total_e) {
        int n = idx / 320, k = idx % 320;
        float v = 0.0f;
        if (n < 128) v = w_edge1[k * 128 + n];
        else if (n < 192) v = w_lin2[k * 64 + (n - 128)];
        else if (n >= 256 && k >= 256) v = w_proj[(k - 256) * 128 + (n - 256)];
        bt_edge[idx] = v;
    } else {
        int id2 = idx - total_e;
        if (id2 < 128 * 320) {
            int n = id2 / 320, k = id2 % 320;
            bt_ang[id2] = (n < 64) ? w_ang[k * 64 + n] : w_ga1[k * 64 + (n - 64)];
        }
    }
}

// ---------------- NAIVE full g1 path (f32, correctness-first) ----------------
__global__ __launch_bounds__(128) void k_g1_naive(
    const float* __restrict__ g1_ext, const float* __restrict__ g2,
    const float* __restrict__ h2, const float* __restrict__ sw,
    const int* __restrict__ nlist,
    const float* __restrict__ w_self, const float* __restrict__ b_self,
    const float* __restrict__ w_proj,
    const float* __restrict__ w_lin1, const float* __restrict__ b_lin1,
    const float* __restrict__ w_edge1, const float* __restrict__ b_edge1,
    float* __restrict__ out_g1) {
    const int l = blockIdx.x, c = threadIdx.x;  // 128 threads
    __shared__ float g1s[128];
    __shared__ float swl[96];
    __shared__ int nll[96];
    __shared__ float hg2[3][64];
    __shared__ float hg1[3][128];
    __shared__ float symv[768];
    g1s[c] = g1_ext[l * 128 + c];
    if (c < 96) { swl[c] = sw[l * 96 + c]; nll[c] = nlist[l * 96 + c]; }
    __syncthreads();

    // term2 = silu(g1 @ w_self + b_self)
    float t2 = b_self[c];
    for (int k = 0; k < 128; k++) t2 += g1s[k] * w_self[k * 128 + c];
    t2 = silu(t2);

    // hg = einsum('blnt,blnd->bltd', h2, g*sw) / sqrt(96)
    const float inv = 0.1020620726f;
    for (int p = c; p < 576; p += 128) {
        float acc = 0.0f;
        if (p < 192) {
            int tt = p / 64, d = p % 64;
            for (int n = 0; n < 96; n++)
                acc += h2[l * 288 + n * 3 + tt] * g2[(l * 96 + n) * 64 + d] * swl[n];
            hg2[tt][d] = acc * inv;
        } else {
            int q = p - 192;
            int tt = q / 128, d = q % 128;
            for (int n = 0; n < 96; n++)
                acc += h2[l * 288 + n * 3 + tt] * g1_ext[nll[n] * 128 + d] * swl[n];
            hg1[tt][d] = acc * inv;
        }
    }
    __syncthreads();
    // symv = [grrg(g2) 256 | grrg(gg1) 512], grrg[d][a] = sum_t hg[t][d]*hg[t][a]
    for (int p = c; p < 768; p += 128) {
        float acc = 0.0f;
        if (p < 256) {
            int d = p >> 2, a = p & 3;
            for (int tt = 0; tt < 3; tt++) acc += hg2[tt][d] * hg2[tt][a];
        } else {
            int q = p - 256;
            int d = q >> 2, a = q & 3;
            for (int tt = 0; tt < 3; tt++) acc += hg1[tt][d] * hg1[tt][a];
        }
        symv[p] = acc;
    }
    __syncthreads();
    // term4 = silu(sym @ w_lin1 + b_lin1)
    float t4 = b_lin1[c];
    for (int k = 0; k < 768; k++) t4 += symv[k] * w_lin1[k * 128 + c];
    t4 = silu(t4);

    // term3 & term5
    float we_g1 = 0.0f;
    for (int k = 0; k < 128; k++) we_g1 += g1s[k] * w_edge1[k * 128 + c];
    float t3 = 0.0f, t5 = 0.0f;
    for (int n = 0; n < 96; n++) {
        const float* gg1row = g1_ext + nll[n] * 128;
        const float* g2row = g2 + (l * 96 + n) * 64;
        float dot = we_g1;
        for (int k = 0; k < 128; k++) dot += gg1row[k] * w_edge1[(128 + k) * 128 + c];
        for (int k = 0; k < 64; k++) dot += g2row[k] * w_edge1[(256 + k) * 128 + c];
        t5 += silu(dot + b_edge1[c]) * swl[n];
        float dp = 0.0f;
        for (int k = 0; k < 64; k++) dp += g2row[k] * w_proj[k * 128 + c];
        t3 += dp * gg1row[c] * swl[n];
    }
    t3 *= (1.0f / 96.0f);
    t5 *= (1.0f / 96.0f);

    out_g1[l * 128 + c] = (g1s[c] + t2 + t3 + t4 + t5) * 0.4472135955f;
}

// ---------------- angle GEMM (MFMA): M=204800 (l,i,j), K=320, N=128 (w_ang|w_ga1) ------
__global__ __launch_bounds__(256) void gemm_angle(
    const float* __restrict__ ae, const float* __restrict__ g1_ext, const float* __restrict__ g2,
    const float* __restrict__ a_sw, const float* __restrict__ bt_ang,
    const float* __restrict__ b_ang, const float* __restrict__ b_ga1,
    float* __restrict__ g2ang_acc, float* __restrict__ a_new_out) {
    const int m0 = blockIdx.x * 128;
    __shared__ __align__(16) unsigned short Asl[128 * 40];
    __shared__ __align__(16) unsigned short Bsl[128 * 40];
    const int tid = threadIdx.x;
    const int lane = tid & 63, wid = tid >> 6;
    const int wr = wid >> 1, wc = wid & 1;
    const int r15 = lane & 15, kg = lane >> 4;
    f32x4 acc[4][4] = {};
    for (int kk = 0; kk < 10; ++kk) {
#pragma unroll
        for (int p = 0; p < 2; ++p) {
            int g = tid + p * 256;
            int row = g >> 2, gr = g & 3;
            int kglob = kk * 32 + gr * 8;
            int r = m0 + row;
            int l = r / 400;
            int rem = r - l * 400;
            int i = rem / 20;
            int j = rem - i * 20;
            const float* src;
            if (kglob < 64)       src = ae + r * 64 + kglob;
            else if (kglob < 192) src = g1_ext + l * 128 + (kglob - 64);
            else if (kglob < 256) src = g2 + (l * 96 + i) * 64 + (kglob - 192);
            else                  src = g2 + (l * 96 + j) * 64 + (kglob - 256);
            cvt8_store(&Asl[row * 40 + gr * 8], src);
            cvt8_store(&Bsl[row * 40 + gr * 8], bt_ang + row * 320 + kglob);
        }
        __syncthreads();
        bf16x8 afr[4], bfr[4];
#pragma unroll
        for (int mi = 0; mi < 4; mi++)
            afr[mi] = *(const bf16x8*)&Asl[(wr * 64 + mi * 16 + r15) * 40 + kg * 8];
#pragma unroll
        for (int ni = 0; ni < 4; ni++)
            bfr[ni] = *(const bf16x8*)&Bsl[(wc * 64 + ni * 16 + r15) * 40 + kg * 8];
#pragma unroll
        for (int mi = 0; mi < 4; mi++)
#pragma unroll
            for (int ni = 0; ni < 4; ni++)
                acc[mi][ni] = __builtin_amdgcn_mfma_f32_16x16x32_bf16(afr[mi], bfr[ni], acc[mi][ni], 0, 0, 0);
        __syncthreads();
    }
#pragma unroll
    for (int mi = 0; mi < 4; mi++) {
        int rbase = m0 + wr * 64 + mi * 16 + kg * 4;
#pragma unroll
        for (int ni = 0; ni < 4; ni++) {
            int c = wc * 64 + ni * 16 + r15;
#pragma unroll
            for (int t2 = 0; t2 < 4; t2++) {
                int r = rbase + t2;
                float z = acc[mi][ni][t2];
                int l = r / 400;
                int rem = r - l * 400;
                int i = rem / 20;
                int j = rem - i * 20;
                if (c < 64) {
                    a_new_out[r * 64 + c] = (ae[r * 64 + c] + silu(z + b_ang[c])) * 0.70710678f;
                } else {
                    int cc = c - 64;
                    float s = a_sw[l * 20 + i] * a_sw[l * 20 + j];
                    float v = silu(s * z + b_ga1[cc]);
                    atomicAdd(&g2ang_acc[(l * 20 + i) * 64 + cc], v);
                }
            }
        }
    }
}

// ---------------- F2: yga2 = silu((g2ang_acc/20) @ w_ga2 + b_ga2) ----------------
__global__ void k_f2(const float* __restrict__ g2ang_acc, const float* __restrict__ w_ga2,
                     const float* __restrict__ b_ga2, float* __restrict__ yga2) {
    int l = blockIdx.x, t = threadIdx.x;  // 256 threads
    __shared__ float gs[20 * 64];
    for (int p = t; p < 1280; p += 256) gs[p] = g2ang_acc[l * 1280 + p] * 0.05f;
    __syncthreads();
    for (int p = t; p < 1280; p += 256) {
        int i = p >> 6, c = p & 63;
        float acc = b_ga2[c];
#pragma unroll 8
        for (int k = 0; k < 64; k++) acc += gs[i * 64 + k] * w_ga2[k * 64 + c];
        yga2[l * 1280 + p] = silu(acc);
    }
}

// ---------------- edge GEMM (MFMA), g2 tile: M=49152, K=320, N=128 (lin2|pad) ------
__global__ __launch_bounds__(256) void gemm_edge_g2(
    const float* __restrict__ g1_ext, const float* __restrict__ g2, const float* __restrict__ sw,
    const int* __restrict__ nlist, const float* __restrict__ bt_edge,
    const float* __restrict__ b_lin2, const float* __restrict__ b_ga2,
    const float* __restrict__ yga2, float* __restrict__ g2_new_out) {
    const int m0 = blockIdx.x * 128;
    __shared__ __align__(16) unsigned short Asl[128 * 40];
    __shared__ __align__(16) unsigned short Bsl[128 * 40];
    const int tid = threadIdx.x;
    const int lane = tid & 63, wid = tid >> 6;
    const int wr = wid >> 1, wc = wid & 1;
    const int r15 = lane & 15, kg = lane >> 4;
    f32x4 acc[4][4] = {};
    for (int kk = 0; kk < 10; ++kk) {
#pragma unroll
        for (int p = 0; p < 2; ++p) {
            int g = tid + p * 256;
            int row = g >> 2, gr = g & 3;
            int kglob = kk * 32 + gr * 8;
            int r = m0 + row;
            int l = r / 96;
            const float* src;
            if (kglob < 128)      src = g1_ext + l * 128 + kglob;
            else if (kglob < 256) src = g1_ext + nlist[r] * 128 + (kglob - 128);
            else                  src = g2 + r * 64 + (kglob - 256);
            cvt8_store(&Asl[row * 40 + gr * 8], src);
            cvt8_store(&Bsl[row * 40 + gr * 8], bt_edge + (128 + row) * 320 + kglob);
        }
        __syncthreads();
        bf16x8 afr[4], bfr[4];
#pragma unroll
        for (int mi = 0; mi < 4; mi++)
            afr[mi] = *(const bf16x8*)&Asl[(wr * 64 + mi * 16 + r15) * 40 + kg * 8];
#pragma unroll
        for (int ni = 0; ni < 4; ni++)
            bfr[ni] = *(const bf16x8*)&Bsl[(wc * 64 + ni * 16 + r15) * 40 + kg * 8];
#pragma unroll
        for (int mi = 0; mi < 4; mi++)
#pragma unroll
            for (int ni = 0; ni < 4; ni++)
                acc[mi][ni] = __builtin_amdgcn_mfma_f32_16x16x32_bf16(afr[mi], bfr[ni], acc[mi][ni], 0, 0, 0);
        __syncthreads();
    }
#pragma unroll
    for (int mi = 0; mi < 4; mi++) {
        int rbase = m0 + wr * 64 + mi * 16 + kg * 4;
#pragma unroll
        for (int ni = 0; ni < 4; ni++) {
            int c = wc * 64 + ni * 16 + r15;
            if (c >= 64) continue;  // cols 64..127 are zero pad
#pragma unroll
            for (int t2 = 0; t2 < 4; t2++) {
                int r = rbase + t2;
                float z = acc[mi][ni][t2];
                int l = r / 96;
                int n = r - l * 96;
                float y = silu(z + b_lin2[c]);
                float yg = (n < ASEL) ? yga2[(l * 20 + n) * 64 + c] : silu(b_ga2[c]);
                g2_new_out[r * 64 + c] = (g2[r * 64 + c] + y + yg) * 0.57735027f;
            }
        }
    }
}

extern "C" void kernel_launch(void* const* d_in, const int* in_sizes, int n_in,
                              void* d_out, int out_size, void* d_ws, size_t ws_size,
                              hipStream_t stream) {
    // insertion-order binding (confirmed on-device by R5's size-fingerprint match)
    if (n_in < 22 || in_sizes[0] != 81920 || in_sizes[3] != 13107200) return;
    const float* g1_ext = (const float*)d_in[0];
    const float* g2     = (const float*)d_in[1];
    const float* h2     = (const float*)d_in[2];
    const float* ae     = (const float*)d_in[3];
    const float* sw     = (const float*)d_in[4];
    const float* a_sw   = (const float*)d_in[5];
    const float* w_self = (const float*)d_in[6];
    const float* b_self = (const float*)d_in[7];
    const float* w_proj = (const float*)d_in[8];
    const float* w_lin1 = (const float*)d_in[9];
    const float* b_lin1 = (const float*)d_in[10];
    const float* w_edge1= (const float*)d_in[11];
    const float* b_edge1= (const float*)d_in[12];
    const float* w_lin2 = (const float*)d_in[13];
    const float* b_lin2 = (const float*)d_in[14];
    const float* w_ang  = (const float*)d_in[15];
    const float* b_ang  = (const float*)d_in[16];
    const float* w_ga1  = (const float*)d_in[17];
    const float* b_ga1  = (const float*)d_in[18];
    const float* w_ga2  = (const float*)d_in[19];
    const float* b_ga2  = (const float*)d_in[20];
    const int*   nlist  = (const int*)d_in[21];

    float* ws = (float*)d_ws;
    float* bt_edge = ws;                 // 122880
    float* bt_ang  = ws + 122880;        // 40960
    float* yga2    = ws + 163840;        // 655360
    float* g2acc   = ws + 819200;        // 655360 (end 1474560 floats = 5.9 MB)
    if (ws_size < (size_t)1474560 * sizeof(float)) return;

    // OUTPUTS ARE FLOAT32 (reference computes in f32; "else float*" harness rule)
    float* out = (float*)d_out;
    float* out_g1 = out;                 // 65536
    float* out_g2 = out + 65536;         // 3145728
    float* out_h2 = out + 3211264;       // 147456
    float* out_an = out + 3358720;       // 13107200

    hipMemsetAsync(g2acc, 0, 655360 * sizeof(float), stream);

    prep_bt<<<640, 256, 0, stream>>>(w_edge1, w_lin2, w_proj, w_ang, w_ga1, bt_edge, bt_ang);
    k_g1_naive<<<512, 128, 0, stream>>>(g1_ext, g2, h2, sw, nlist, w_self, b_self, w_proj,
                                        w_lin1, b_lin1, w_edge1, b_edge1, out_g1);
    gemm_angle<<<1600, 256, 0, stream>>>(ae, g1_ext, g2, a_sw, bt_ang, b_ang, b_ga1, g2acc, out_an);
    k_f2<<<512, 256, 0, stream>>>(g2acc, w_ga2, b_ga2, yga2);
    gemm_edge_g2<<<384, 256, 0, stream>>>(g1_ext, g2, sw, nlist, bt_edge, b_lin2, b_ga2,
                                          yga2, out_g2);
    // h2 passes through unchanged (f32 -> f32): device-to-device copy
    hipMemcpyAsync(out_h2, h2, 147456 * sizeof(float), hipMemcpyDeviceToDevice, stream);
}

// Round 8
// 232.288 us; speedup vs baseline: 2.8195x; 2.8195x over previous
//
#include <hip/hip_runtime.h>
#include <hip/hip_bf16.h>

// Problem constants
#define NLOC 512
#define NALL 640
#define NNEI 96
#define ASEL 20
#define NDIM 128
#define EDIM 64
#define ADIM 64

typedef short bf16x8 __attribute__((ext_vector_type(8)));
typedef float f32x4 __attribute__((ext_vector_type(4)));
typedef unsigned short ushort8 __attribute__((ext_vector_type(8)));

__device__ __forceinline__ unsigned short f2bf(float f) {
    unsigned int u = __float_as_uint(f);
    unsigned int r = (u + 0x7FFFu + ((u >> 16) & 1u)) >> 16;
    return (unsigned short)r;
}

__device__ __forceinline__ float silu(float x) { return x / (1.0f + __expf(-x)); }

// convert 8 consecutive f32 -> 8 bf16, store 16B to LDS
__device__ __forceinline__ void cvt8_store(unsigned short* dst, const float* src) {
    float4 f0 = *(const float4*)src;
    float4 f1 = *(const float4*)(src + 4);
    ushort8 v;
    v[0] = f2bf(f0.x); v[1] = f2bf(f0.y); v[2] = f2bf(f0.z); v[3] = f2bf(f0.w);
    v[4] = f2bf(f1.x); v[5] = f2bf(f1.y); v[6] = f2bf(f1.z); v[7] = f2bf(f1.w);
    *(ushort8*)dst = v;
}

// ---------------- prep: build N-major (transposed) weight matrices in ws ----------------
// bt_edge: [384][320]  n<128: w_edge1 | n<192: w_lin2 | n<256: pad | n<384: w_proj(k>=256)
// bt_ang : [128][320]  n<64: w_ang | n<128: w_ga1
__global__ void prep_bt(const float* __restrict__ w_edge1, const float* __restrict__ w_lin2,
                        const float* __restrict__ w_proj, const float* __restrict__ w_ang,
                        const float* __restrict__ w_ga1, float* __restrict__ bt_edge,
                        float* __restrict__ bt_ang) {
    int idx = blockIdx.x * 256 + threadIdx.x;
    const int total_e = 384 * 320;
    if (idx < total_e) {
        int n = idx / 320, k = idx % 320;
        float v = 0.0f;
        if (n < 128) v = w_edge1[k * 128 + n];
        else if (n < 192) v = w_lin2[k * 64 + (n - 128)];
        else if (n >= 256 && k >= 256) v = w_proj[(k - 256) * 128 + (n - 256)];
        bt_edge[idx] = v;
    } else {
        int id2 = idx - total_e;
        if (id2 < 128 * 320) {
            int n = id2 / 320, k = id2 % 320;
            bt_ang[id2] = (n < 64) ? w_ang[k * 64 + n] : w_ga1[k * 64 + (n - 64)];
        }
    }
}

// ---------------- g1self = silu(g1 @ w_self + b_self) ----------------
__global__ void k_g1self(const float* __restrict__ g1_ext, const float* __restrict__ w_self,
                         const float* __restrict__ b_self, float* __restrict__ g1self) {
    int l = blockIdx.x, c = threadIdx.x;  // 128 threads
    __shared__ float g1s[128];
    g1s[c] = g1_ext[l * 128 + c];
    __syncthreads();
    float acc = b_self[c];
#pragma unroll 8
    for (int k = 0; k < 128; k++) acc += g1s[k] * w_self[k * 128 + c];
    g1self[l * 128 + c] = silu(acc);
}

// ---------------- sym op + term4 = silu(sym @ w_lin1 + b_lin1) ----------------
__global__ void k_sym(const float* __restrict__ g1_ext, const float* __restrict__ g2,
                      const float* __restrict__ h2, const float* __restrict__ sw,
                      const int* __restrict__ nlist, const float* __restrict__ w_lin1,
                      const float* __restrict__ b_lin1, float* __restrict__ term4) {
    int l = blockIdx.x, t = threadIdx.x;  // 256 threads
    __shared__ float h2s[96 * 3];
    __shared__ float sws[96];
    __shared__ int nls[96];
    __shared__ float hg[3 * 192];  // [tt][0:64]=hg2, [tt][64:192]=hg1
    __shared__ float symv[768];
    if (t < 96) { sws[t] = sw[l * 96 + t]; nls[t] = nlist[l * 96 + t]; }
    for (int p = t; p < 288; p += 256) h2s[p] = h2[l * 288 + p];
    __syncthreads();
    const float inv = 0.1020620726f;  // 1/sqrt(96)
    for (int p = t; p < 576; p += 256) {
        float acc = 0.0f;
        if (p < 192) {
            int tt = p >> 6, d = p & 63;
            for (int n = 0; n < 96; n++)
                acc += h2s[n * 3 + tt] * g2[(l * 96 + n) * 64 + d] * sws[n];
            hg[tt * 192 + d] = acc * inv;
        } else {
            int q = p - 192;
            int tt = q >> 7, d = q & 127;
            for (int n = 0; n < 96; n++)
                acc += h2s[n * 3 + tt] * g1_ext[nls[n] * 128 + d] * sws[n];
            hg[tt * 192 + 64 + d] = acc * inv;
        }
    }
    __syncthreads();
    for (int p = t; p < 768; p += 256) {
        float acc = 0.0f;
        if (p < 256) {
            int d = p >> 2, a = p & 3;
            for (int tt = 0; tt < 3; tt++) acc += hg[tt * 192 + d] * hg[tt * 192 + a];
        } else {
            int q = p - 256;
            int d = q >> 2, a = q & 3;
            for (int tt = 0; tt < 3; tt++) acc += hg[tt * 192 + 64 + d] * hg[tt * 192 + 64 + a];
        }
        symv[p] = acc;
    }
    __syncthreads();
    if (t < 128) {
        float acc = b_lin1[t];
#pragma unroll 8
        for (int k = 0; k < 768; k++) acc += symv[k] * w_lin1[k * 128 + t];
        term4[l * 128 + t] = silu(acc);
    }
}

// ---------------- angle GEMM (MFMA): M=204800 (l,i,j), K=320, N=128 (w_ang|w_ga1) ------
__global__ __launch_bounds__(256) void gemm_angle(
    const float* __restrict__ ae, const float* __restrict__ g1_ext, const float* __restrict__ g2,
    const float* __restrict__ a_sw, const float* __restrict__ bt_ang,
    const float* __restrict__ b_ang, const float* __restrict__ b_ga1,
    float* __restrict__ g2ang_acc, float* __restrict__ a_new_out) {
    const int m0 = blockIdx.x * 128;
    __shared__ __align__(16) unsigned short Asl[128 * 40];
    __shared__ __align__(16) unsigned short Bsl[128 * 40];
    const int tid = threadIdx.x;
    const int lane = tid & 63, wid = tid >> 6;
    const int wr = wid >> 1, wc = wid & 1;
    const int r15 = lane & 15, kg = lane >> 4;
    f32x4 acc[4][4] = {};
    for (int kk = 0; kk < 10; ++kk) {
#pragma unroll
        for (int p = 0; p < 2; ++p) {
            int g = tid + p * 256;
            int row = g >> 2, gr = g & 3;
            int kglob = kk * 32 + gr * 8;
            int r = m0 + row;
            int l = r / 400;
            int rem = r - l * 400;
            int i = rem / 20;
            int j = rem - i * 20;
            const float* src;
            if (kglob < 64)       src = ae + r * 64 + kglob;
            else if (kglob < 192) src = g1_ext + l * 128 + (kglob - 64);
            else if (kglob < 256) src = g2 + (l * 96 + i) * 64 + (kglob - 192);
            else                  src = g2 + (l * 96 + j) * 64 + (kglob - 256);
            cvt8_store(&Asl[row * 40 + gr * 8], src);
            cvt8_store(&Bsl[row * 40 + gr * 8], bt_ang + row * 320 + kglob);
        }
        __syncthreads();
        bf16x8 afr[4], bfr[4];
#pragma unroll
        for (int mi = 0; mi < 4; mi++)
            afr[mi] = *(const bf16x8*)&Asl[(wr * 64 + mi * 16 + r15) * 40 + kg * 8];
#pragma unroll
        for (int ni = 0; ni < 4; ni++)
            bfr[ni] = *(const bf16x8*)&Bsl[(wc * 64 + ni * 16 + r15) * 40 + kg * 8];
#pragma unroll
        for (int mi = 0; mi < 4; mi++)
#pragma unroll
            for (int ni = 0; ni < 4; ni++)
                acc[mi][ni] = __builtin_amdgcn_mfma_f32_16x16x32_bf16(afr[mi], bfr[ni], acc[mi][ni], 0, 0, 0);
        __syncthreads();
    }
    // epilogue. 4-aligned row blocks never cross an (l,i) boundary (20%4==0):
    // sum the 4 t2-values locally -> 1 atomic instead of 4.
#pragma unroll
    for (int mi = 0; mi < 4; mi++) {
        int rbase = m0 + wr * 64 + mi * 16 + kg * 4;
        int l = rbase / 400;
        int rem = rbase - l * 400;
        int i = rem / 20;
        int j0 = rem - i * 20;
#pragma unroll
        for (int ni = 0; ni < 4; ni++) {
            int c = wc * 64 + ni * 16 + r15;
            if (c < 64) {
#pragma unroll
                for (int t2 = 0; t2 < 4; t2++) {
                    int r = rbase + t2;
                    a_new_out[r * 64 + c] =
                        (ae[r * 64 + c] + silu(acc[mi][ni][t2] + b_ang[c])) * 0.70710678f;
                }
            } else {
                int cc = c - 64;
                float swi = a_sw[l * 20 + i];
                float part = 0.0f;
#pragma unroll
                for (int t2 = 0; t2 < 4; t2++) {
                    float s = swi * a_sw[l * 20 + j0 + t2];
                    part += silu(s * acc[mi][ni][t2] + b_ga1[cc]);
                }
                atomicAdd(&g2ang_acc[(l * 20 + i) * 64 + cc], part);
            }
        }
    }
}

// ---------------- F2: yga2 = silu((g2ang_acc/20) @ w_ga2 + b_ga2) ----------------
__global__ void k_f2(const float* __restrict__ g2ang_acc, const float* __restrict__ w_ga2,
                     const float* __restrict__ b_ga2, float* __restrict__ yga2) {
    int l = blockIdx.x, t = threadIdx.x;  // 256 threads
    __shared__ float gs[20 * 64];
    for (int p = t; p < 1280; p += 256) gs[p] = g2ang_acc[l * 1280 + p] * 0.05f;
    __syncthreads();
    for (int p = t; p < 1280; p += 256) {
        int i = p >> 6, c = p & 63;
        float acc = b_ga2[c];
#pragma unroll 8
        for (int k = 0; k < 64; k++) acc += gs[i * 64 + k] * w_ga2[k * 64 + c];
        yga2[l * 1280 + p] = silu(acc);
    }
}

// ---------------- edge GEMM (MFMA): M=49152 (l,n), K=320, ntile: 0=edge1,1=lin2,2=proj --
__global__ __launch_bounds__(256) void gemm_edge(
    const float* __restrict__ g1_ext, const float* __restrict__ g2, const float* __restrict__ sw,
    const int* __restrict__ nlist, const float* __restrict__ bt_edge,
    const float* __restrict__ b_edge1, const float* __restrict__ b_lin2,
    const float* __restrict__ b_ga2, const float* __restrict__ yga2,
    float* __restrict__ g1_acc3, float* __restrict__ g1_acc5,
    float* __restrict__ g2_new_out) {
    const int m0 = blockIdx.x * 128;
    const int ntile = blockIdx.y;
    const int kk0 = (ntile == 2) ? 8 : 0;  // proj cols only touch k>=256
    __shared__ __align__(16) unsigned short Asl[128 * 40];
    __shared__ __align__(16) unsigned short Bsl[128 * 40];
    const int tid = threadIdx.x;
    const int lane = tid & 63, wid = tid >> 6;
    const int wr = wid >> 1, wc = wid & 1;
    const int r15 = lane & 15, kg = lane >> 4;
    f32x4 acc[4][4] = {};
    for (int kk = kk0; kk < 10; ++kk) {
#pragma unroll
        for (int p = 0; p < 2; ++p) {
            int g = tid + p * 256;
            int row = g >> 2, gr = g & 3;
            int kglob = kk * 32 + gr * 8;
            int r = m0 + row;
            int l = r / 96;
            const float* src;
            if (kglob < 128)      src = g1_ext + l * 128 + kglob;
            else if (kglob < 256) src = g1_ext + nlist[r] * 128 + (kglob - 128);
            else                  src = g2 + r * 64 + (kglob - 256);
            cvt8_store(&Asl[row * 40 + gr * 8], src);
            cvt8_store(&Bsl[row * 40 + gr * 8], bt_edge + (ntile * 128 + row) * 320 + kglob);
        }
        __syncthreads();
        bf16x8 afr[4], bfr[4];
#pragma unroll
        for (int mi = 0; mi < 4; mi++)
            afr[mi] = *(const bf16x8*)&Asl[(wr * 64 + mi * 16 + r15) * 40 + kg * 8];
#pragma unroll
        for (int ni = 0; ni < 4; ni++)
            bfr[ni] = *(const bf16x8*)&Bsl[(wc * 64 + ni * 16 + r15) * 40 + kg * 8];
#pragma unroll
        for (int mi = 0; mi < 4; mi++)
#pragma unroll
            for (int ni = 0; ni < 4; ni++)
                acc[mi][ni] = __builtin_amdgcn_mfma_f32_16x16x32_bf16(afr[mi], bfr[ni], acc[mi][ni], 0, 0, 0);
        __syncthreads();
    }
    // epilogue. 4-aligned row blocks never cross an l boundary (96%4==0):
    // local t2-sum -> 1 atomic per (thread, c) for tiles 0 and 2.
#pragma unroll
    for (int mi = 0; mi < 4; mi++) {
        int rbase = m0 + wr * 64 + mi * 16 + kg * 4;
        int l = rbase / 96;
        int n0 = rbase - l * 96;
#pragma unroll
        for (int ni = 0; ni < 4; ni++) {
            int c = wc * 64 + ni * 16 + r15;
            if (ntile == 0) {
                float part = 0.0f;
#pragma unroll
                for (int t2 = 0; t2 < 4; t2++)
                    part += silu(acc[mi][ni][t2] + b_edge1[c]) * sw[rbase + t2];
                atomicAdd(&g1_acc5[l * 128 + c], part);
            } else if (ntile == 1) {
                if (c < 64) {
#pragma unroll
                    for (int t2 = 0; t2 < 4; t2++) {
                        int r = rbase + t2;
                        int n = n0 + t2;
                        float y = silu(acc[mi][ni][t2] + b_lin2[c]);
                        float yg = (n < ASEL) ? yga2[(l * 20 + n) * 64 + c] : silu(b_ga2[c]);
                        g2_new_out[r * 64 + c] = (g2[r * 64 + c] + y + yg) * 0.57735027f;
                    }
                }
            } else {
                float part = 0.0f;
#pragma unroll
                for (int t2 = 0; t2 < 4; t2++) {
                    int r = rbase + t2;
                    part += acc[mi][ni][t2] * g1_ext[nlist[r] * 128 + c] * sw[r];
                }
                atomicAdd(&g1_acc3[l * 128 + c], part);
            }
        }
    }
}

// ---------------- F1: g1_new ----------------
__global__ void k_f1(const float* __restrict__ g1_ext, const float* __restrict__ g1self,
                     const float* __restrict__ acc3, const float* __restrict__ term4,
                     const float* __restrict__ acc5, float* __restrict__ out_g1) {
    int idx = blockIdx.x * 256 + threadIdx.x;  // 65536
    float v = g1_ext[idx] + g1self[idx] + acc3[idx] * (1.0f / 96.0f) + term4[idx] +
              acc5[idx] * (1.0f / 96.0f);
    out_g1[idx] = v * 0.4472135955f;
}

extern "C" void kernel_launch(void* const* d_in, const int* in_sizes, int n_in,
                              void* d_out, int out_size, void* d_ws, size_t ws_size,
                              hipStream_t stream) {
    if (n_in < 22 || in_sizes[0] != 81920 || in_sizes[3] != 13107200) return;
    const float* g1_ext = (const float*)d_in[0];
    const float* g2     = (const float*)d_in[1];
    const float* h2     = (const float*)d_in[2];
    const float* ae     = (const float*)d_in[3];
    const float* sw     = (const float*)d_in[4];
    const float* a_sw   = (const float*)d_in[5];
    const float* w_self = (const float*)d_in[6];
    const float* b_self = (const float*)d_in[7];
    const float* w_proj = (const float*)d_in[8];
    const float* w_lin1 = (const float*)d_in[9];
    const float* b_lin1 = (const float*)d_in[10];
    const float* w_edge1= (const float*)d_in[11];
    const float* b_edge1= (const float*)d_in[12];
    const float* w_lin2 = (const float*)d_in[13];
    const float* b_lin2 = (const float*)d_in[14];
    const float* w_ang  = (const float*)d_in[15];
    const float* b_ang  = (const float*)d_in[16];
    const float* w_ga1  = (const float*)d_in[17];
    const float* b_ga1  = (const float*)d_in[18];
    const float* w_ga2  = (const float*)d_in[19];
    const float* b_ga2  = (const float*)d_in[20];
    const int*   nlist  = (const int*)d_in[21];

    // ws layout (floats): bt_edge 122880 | bt_ang 40960 | g1self 65536 | term4 65536
    //   | yga2 655360 | acc3 65536 | acc5 65536 | g2acc 655360  -> total 1736704
    float* ws = (float*)d_ws;
    float* bt_edge = ws;
    float* bt_ang  = ws + 122880;
    float* g1self  = ws + 163840;
    float* term4   = ws + 229376;
    float* yga2    = ws + 294912;
    float* acc3    = ws + 950272;
    float* acc5    = ws + 1015808;
    float* g2acc   = ws + 1081344;
    if (ws_size < (size_t)1736704 * sizeof(float)) return;

    float* out = (float*)d_out;
    float* out_g1 = out;                 // 65536
    float* out_g2 = out + 65536;         // 3145728
    float* out_h2 = out + 3211264;       // 147456
    float* out_an = out + 3358720;       // 13107200

    // acc3, acc5, g2acc are contiguous: one memset for all three
    hipMemsetAsync(acc3, 0, (65536 + 65536 + 655360) * sizeof(float), stream);

    prep_bt<<<640, 256, 0, stream>>>(w_edge1, w_lin2, w_proj, w_ang, w_ga1, bt_edge, bt_ang);
    k_g1self<<<512, 128, 0, stream>>>(g1_ext, w_self, b_self, g1self);
    k_sym<<<512, 256, 0, stream>>>(g1_ext, g2, h2, sw, nlist, w_lin1, b_lin1, term4);
    gemm_angle<<<1600, 256, 0, stream>>>(ae, g1_ext, g2, a_sw, bt_ang, b_ang, b_ga1, g2acc, out_an);
    k_f2<<<512, 256, 0, stream>>>(g2acc, w_ga2, b_ga2, yga2);
    gemm_edge<<<dim3(384, 3), 256, 0, stream>>>(g1_ext, g2, sw, nlist, bt_edge, b_edge1, b_lin2,
                                                b_ga2, yga2, acc3, acc5, out_g2);
    k_f1<<<256, 256, 0, stream>>>(g1_ext, g1self, acc3, term4, acc5, out_g1);
    hipMemcpyAsync(out_h2, h2, 147456 * sizeof(float), hipMemcpyDeviceToDevice, stream);
}